// Round 3
// baseline (154.658 us; speedup 1.0000x reference)
//
#include <hip/hip_runtime.h>

#define NN 4096
#define MTOT 9
#define CH 128

// -------- Wigner-3j / TP constants (verified correct in earlier passes) ----
#define S3f 0.57735026918962576f   // 1/sqrt(3)
#define S2f 0.70710678118654752f   // 1/sqrt(2)
#define CUf 0.54772255750516611f   // sqrt(3/10)
#define CVf 0.31622776601683794f   // sqrt(1/10)
#define CWf 0.63245553203367587f   // 2/sqrt(10)
#define CAf 0.40824829046386302f   // 1/sqrt(6)
#define CA2f 0.81649658092772603f  // 2/sqrt(6)
#define YSf ((float)(2.04665350914 * 0.48860251190291992))

typedef __attribute__((ext_vector_type(8))) short short8;
typedef __attribute__((ext_vector_type(4))) float f32x4;
typedef __attribute__((ext_vector_type(2))) float f32x2;

__device__ __forceinline__ unsigned short f2b(float f) {
  unsigned u = __builtin_bit_cast(unsigned, f);
  u += 0x7FFFu + ((u >> 16) & 1u);           // RNE
  return (unsigned short)(u >> 16);
}

// ---------------- W pre-swizzle: fp32 [3,128,128] -> bf16 frag-order -------
// out[l*16384 + (((n>>4)*16 + kq)*16 + (n&15))*8 + j] = W[l][kq*8+j][n]
__global__ __launch_bounds__(256) void wprep(
    const float* __restrict__ w1, const float* __restrict__ w2,
    unsigned short* __restrict__ o1, unsigned short* __restrict__ o2)
{
  int g = blockIdx.x * 256 + threadIdx.x;    // 12288 total
  const float* W = w1;
  unsigned short* O = o1;
  int r = g;
  if (r >= 6144) { r -= 6144; W = w2; O = o2; }
  int l  = r >> 11;          // 2048 per l
  int r2 = r & 2047;
  int n  = r2 >> 4;
  int kq = r2 & 15;
  const float* src = W + l * 16384 + kq * 8 * CH + n;
  short8 v;
  #pragma unroll
  for (int j = 0; j < 8; ++j) v[j] = (short)f2b(src[j * CH]);
  *(short8*)(O + (size_t)l * 16384 + (((n >> 4) * 16 + kq) * 16 + (n & 15)) * 8) = v;
}

// ---------------- so3_linear via MFMA 16x16x32 bf16 (first linear) ---------
// YT=1: write bf16 in TRANSPOSED per-node layout for the gather kernel:
//   short index = node*1536 + (c>>1)*24 + m*2 + (c&1)
// i.e. node block = 64 chan-pairs x 12 dwords (9 used + 3 pad) = 3072 B,
// lane p reads its 9 m-dwords contiguously at byte node*3072 + p*48.
template <int XBF, int YT, int NORM>
__global__ __launch_bounds__(256) void so3lin_mfma(
    const void* __restrict__ Xv, const unsigned short* __restrict__ Wsw,
    const float* __restrict__ bias, void* __restrict__ Yv)
{
  __shared__ unsigned short Bs[16384];   // 32 KB frag-order bf16 W_l
  const int bid = blockIdx.x;
  int l, blk0, m0, nm;
  if (bid < 64)       { l = 0; blk0 = bid;       m0 = 0; nm = 1; }
  else if (bid < 256) { l = 1; blk0 = bid - 64;  m0 = 1; nm = 3; }
  else                { l = 2; blk0 = bid - 256; m0 = 4; nm = 5; }
  const int t = threadIdx.x;

  {
    const float4* src = (const float4*)(Wsw + (size_t)l * 16384);
    float4* dst = (float4*)Bs;
    #pragma unroll
    for (int i = 0; i < 8; ++i) dst[t + i * 256] = src[t + i * 256];
  }
  __syncthreads();

  const int lane = t & 63;
  const int wave = t >> 6;
  const int c16  = lane & 15;
  const int quad = lane >> 4;
  const int rb   = (blk0 * 4 + wave) * 16;

  const int ra = rb + c16;
  const int nodeA = ra / nm;
  const int mA = m0 + (ra - nodeA * nm);
  const size_t abase = ((size_t)nodeA * MTOT + mA) * CH + quad * 8;

  f32x4 acc[8] = {};
  #pragma unroll
  for (int kk = 0; kk < CH; kk += 32) {
    short8 afrag;
    if (XBF) {
      afrag = *(const short8*)((const unsigned short*)Xv + abase + kk);
    } else {
      const float* xp = (const float*)Xv + abase + kk;
      float4 f0 = *(const float4*)xp;
      float4 f1 = *(const float4*)(xp + 4);
      afrag = (short8){(short)f2b(f0.x), (short)f2b(f0.y), (short)f2b(f0.z), (short)f2b(f0.w),
                       (short)f2b(f1.x), (short)f2b(f1.y), (short)f2b(f1.z), (short)f2b(f1.w)};
    }
    const int kq = (kk >> 3) + quad;
    #pragma unroll
    for (int ct = 0; ct < 8; ++ct) {
      short8 bfrag = *(const short8*)&Bs[((ct * 16 + kq) * 16 + c16) * 8];
      acc[ct] = __builtin_amdgcn_mfma_f32_16x16x32_bf16(afrag, bfrag, acc[ct], 0, 0, 0);
    }
  }

  const float scale = NORM ? (l == 0 ? 1.0f : (l == 1 ? S3f : S2f)) : 1.0f;
  #pragma unroll
  for (int i = 0; i < 4; ++i) {
    int r2 = rb + quad * 4 + i;
    int node2 = r2 / nm;
    int m2 = m0 + (r2 - node2 * nm);
    #pragma unroll
    for (int ct = 0; ct < 8; ++ct) {
      float v = acc[ct][i];
      if (l == 0) v += bias[ct * 16 + c16];
      v *= scale;
      if (YT) {
        int c = ct * 16 + c16;
        ((unsigned short*)Yv)[(size_t)node2 * 1536 + (c >> 1) * 24 + m2 * 2 + (c & 1)] = f2b(v);
      } else {
        ((float*)Yv)[((size_t)node2 * MTOT + m2) * CH + c16 + ct * 16] = v;
      }
    }
  }
}

// ------- gather + 4-way aggregate + fused TP + fused W2 linear (MFMA) ------
// Structure is the VERIFIED Round-1 kernel (4 waves = 4 nodes/block, full-m
// accumulators, identical TP / At staging / MFMA / epilogue).  Only the load
// side changed: eh1T transposed layout -> 3 vector loads per neighbor,
// issued in batches of 4 neighbors (4 latency exposures instead of ~8).
#define PADK 136   // row stride in shorts: 272 B, multiple of 16 for b128
__global__ __launch_bounds__(256) void agg_tp_w2(
    const unsigned short* __restrict__ X,   // eh1T bf16 transposed [NN][1536]
    const float* __restrict__ pos,
    const float* __restrict__ exp_pos,
    const float* __restrict__ alpha,
    const int*   __restrict__ idx,
    const float* __restrict__ tpw,
    const unsigned short* __restrict__ Wsw, // w2s swizzled bf16 [3*16384]
    const float* __restrict__ bias,         // w2b [128]
    float* __restrict__ out)                // fp32 [NN,9,128]
{
  __shared__ int   sIdx[4][16];
  __shared__ float sAl[4][128];
  __shared__ float sEy[4][48];
  __shared__ float sY[4][4];
  __shared__ __align__(16) unsigned short At[4 * 16 * PADK];  // 17 KB dif tiles
  const int t = threadIdx.x, wave = t >> 6, lane = t & 63;
  const int b = blockIdx.x * 4 + wave;

  if (lane < 16) sIdx[wave][lane] = idx[b * 16 + lane];
  sAl[wave][lane]      = alpha[b * 128 + lane];
  sAl[wave][lane + 64] = alpha[b * 128 + lane + 64];
  if (lane < 3) sY[wave][lane] = YSf * pos[b * 3 + lane];
  __syncthreads();
  if (lane < 48) {
    int j = lane / 3, cmp = lane - 3 * j;
    sEy[wave][lane] = YSf * exp_pos[sIdx[wave][j] * 3 + cmp];
  }
  __syncthreads();

  const int h = lane >> 3;
  const int c0 = lane * 2;
  f32x2 A0[9] = {}, A1[9] = {}, A2[9] = {}, A3[9] = {};
  for (int jb = 0; jb < 16; jb += 4) {
    uint4 qa[4], qb[4]; unsigned qc[4];
    #pragma unroll
    for (int jj = 0; jj < 4; ++jj) {
      const char* src = (const char*)X + (size_t)sIdx[wave][jb + jj] * 3072 + lane * 48;
      qa[jj] = *(const uint4*)(src);
      qb[jj] = *(const uint4*)(src + 16);
      qc[jj] = *(const unsigned*)(src + 32);
    }
    #pragma unroll
    for (int jj = 0; jj < 4; ++jj) {
      const int j = jb + jj;
      float al = sAl[wave][j * 8 + h];
      float e0 = al * sEy[wave][j * 3 + 0];
      float e1 = al * sEy[wave][j * 3 + 1];
      float e2 = al * sEy[wave][j * 3 + 2];
      f32x2 alv = {al, al};
      f32x2 e0v = {e0, e0};
      f32x2 e1v = {e1, e1};
      f32x2 e2v = {e2, e2};
      unsigned vv[9];
      vv[0] = qa[jj].x; vv[1] = qa[jj].y; vv[2] = qa[jj].z; vv[3] = qa[jj].w;
      vv[4] = qb[jj].x; vv[5] = qb[jj].y; vv[6] = qb[jj].z; vv[7] = qb[jj].w;
      vv[8] = qc[jj];
      #pragma unroll
      for (int m = 0; m < 9; ++m) {
        unsigned v = vv[m];
        f32x2 x;
        x.x = __builtin_bit_cast(float, v << 16);
        x.y = __builtin_bit_cast(float, v & 0xFFFF0000u);
        A0[m] += alv * x; A1[m] += e0v * x; A2[m] += e1v * x; A3[m] += e2v * x;
      }
    }
  }

  const float y0 = sY[wave][0], yv1 = sY[wave][1], y2 = sY[wave][2];
  float OUT[9][2];
  #pragma unroll
  for (int ch = 0; ch < 2; ++ch) {
    const int c = c0 + ch;
    const float w0 = tpw[c], w1 = tpw[CH + c], w2 = tpw[2 * CH + c];
    const float w3 = tpw[3 * CH + c], w4 = tpw[4 * CH + c], w5 = tpw[5 * CH + c];
    const float x0 = A0[0][ch];
    const float p0 = A0[1][ch], p1 = A0[2][ch], p2 = A0[3][ch];
    const float d0 = A0[4][ch], d1 = A0[5][ch], d2 = A0[6][ch], d3 = A0[7][ch], d4 = A0[8][ch];

    float r0 = w1 * S3f * (p0 * y0 + p1 * yv1 + p2 * y2);
    float r1 = w0 * x0 * y0 + w2 * S2f * (p1 * y2 - p2 * yv1)
             + w4 * (CUf * (d0 * y2 + d1 * yv1 - d4 * y0) - CVf * d2 * y0);
    float r2 = w0 * x0 * yv1 + w2 * S2f * (p2 * y0 - p0 * y2)
             + w4 * (CUf * (d1 * y0 + d3 * y2) + CWf * d2 * yv1);
    float r3 = w0 * x0 * y2 + w2 * S2f * (p0 * yv1 - p1 * y0)
             + w4 * (CUf * (d0 * y0 + d4 * y2 + d3 * yv1) - CVf * d2 * y2);
    float r4 = w3 * S2f * (p0 * y2 + p2 * y0)
             + w5 * (CAf * (d3 * y2 - d1 * y0) - 2.f * CAf * d4 * yv1);
    float r5 = w3 * S2f * (p0 * yv1 + p1 * y0)
             + w5 * (CAf * (d0 * y0 - d3 * yv1 + d4 * y2) + S2f * d2 * y2);
    float r6 = w3 * (CA2f * p1 * yv1 - CAf * (p0 * y0 + p2 * y2))
             + w5 * S2f * (d3 * y0 - d1 * y2);
    float r7 = w3 * S2f * (p1 * y2 + p2 * yv1)
             + w5 * (CAf * (d1 * yv1 - d0 * y2 + d4 * y0) - S2f * d2 * y0);
    float r8 = w3 * S2f * (p2 * y2 - p0 * y0)
             + w5 * CAf * (2.f * d0 * yv1 - d1 * y2 - d3 * y0);

    float q0 = w1 * S3f * (A1[1][ch] + A2[2][ch] + A3[3][ch]);
    float q1 = w0 * A1[0][ch] + w2 * S2f * (A3[2][ch] - A2[3][ch])
             + w4 * (CUf * (A3[4][ch] + A2[5][ch] - A1[8][ch]) - CVf * A1[6][ch]);
    float q2 = w0 * A2[0][ch] + w2 * S2f * (A1[3][ch] - A3[1][ch])
             + w4 * (CUf * (A1[5][ch] + A3[7][ch]) + CWf * A2[6][ch]);
    float q3 = w0 * A3[0][ch] + w2 * S2f * (A2[1][ch] - A1[2][ch])
             + w4 * (CUf * (A1[4][ch] + A3[8][ch] + A2[7][ch]) - CVf * A3[6][ch]);
    float q4 = w3 * S2f * (A3[1][ch] + A1[3][ch])
             + w5 * (CAf * (A3[7][ch] - A1[5][ch]) - 2.f * CAf * A2[8][ch]);
    float q5 = w3 * S2f * (A2[1][ch] + A1[2][ch])
             + w5 * (CAf * (A1[4][ch] - A2[7][ch] + A3[8][ch]) + S2f * A3[6][ch]);
    float q6 = w3 * (CA2f * A2[2][ch] - CAf * (A1[1][ch] + A3[3][ch]))
             + w5 * S2f * (A1[7][ch] - A3[5][ch]);
    float q7 = w3 * S2f * (A3[2][ch] + A2[3][ch])
             + w5 * (CAf * (A2[5][ch] - A3[4][ch] + A1[8][ch]) - S2f * A1[6][ch]);
    float q8 = w3 * S2f * (A3[3][ch] - A1[1][ch])
             + w5 * CAf * (2.f * A2[4][ch] - A3[5][ch] - A1[7][ch]);

    OUT[0][ch] = r0 - q0; OUT[1][ch] = r1 - q1; OUT[2][ch] = r2 - q2;
    OUT[3][ch] = r3 - q3; OUT[4][ch] = r4 - q4; OUT[5][ch] = r5 - q5;
    OUT[6][ch] = r6 - q6; OUT[7][ch] = r7 - q7; OUT[8][ch] = r8 - q8;
  }

  // ---- Phase 2: stage dif rows (bf16, packed dwords) into A-frag tiles ----
  // row map: m=0 -> tile0 row w ; m=1..3 -> tile1 row w*3+(m-1)
  //          m=4..8 -> g=w*5+(m-4): tile 2+(g>>4), row g&15
  #pragma unroll
  for (int m = 0; m < 9; ++m) {
    int tt, rr;
    if (m == 0)      { tt = 0; rr = wave; }
    else if (m < 4)  { tt = 1; rr = wave * 3 + (m - 1); }
    else             { int g = wave * 5 + (m - 4); tt = 2 + (g >> 4); rr = g & 15; }
    unsigned dw = (unsigned)f2b(OUT[m][0]) | ((unsigned)f2b(OUT[m][1]) << 16);
    *(unsigned*)&At[(tt * 16 + rr) * PADK + c0] = dw;
  }
  __syncthreads();

  // ---- Phase 3: per-wave MFMA tile against w2s fragments (global, L2-hot) -
  const int c16  = lane & 15;
  const int quad = lane >> 4;
  const int l2i  = (wave == 0) ? 0 : (wave == 1 ? 1 : 2);
  const unsigned short* Wl = Wsw + (size_t)l2i * 16384;

  f32x4 acc[8] = {};
  #pragma unroll
  for (int kk = 0; kk < CH; kk += 32) {
    short8 afrag = *(const short8*)&At[(wave * 16 + c16) * PADK + quad * 8 + kk];
    const int kq = (kk >> 3) + quad;
    #pragma unroll
    for (int ct = 0; ct < 8; ++ct) {
      short8 bfrag = *(const short8*)&Wl[((ct * 16 + kq) * 16 + c16) * 8];
      acc[ct] = __builtin_amdgcn_mfma_f32_16x16x32_bf16(afrag, bfrag, acc[ct], 0, 0, 0);
    }
  }

  // ---- Phase 4: bias (l0) + per-l scale, store fp32 ----
  const float scale = (wave == 0) ? 1.0f : (wave == 1 ? S3f : S2f);
  const int rmax = (wave == 1) ? 12 : ((wave == 2) ? 16 : 4);
  #pragma unroll
  for (int i = 0; i < 4; ++i) {
    int rr = quad * 4 + i;
    if (rr < rmax) {
      int node, m;
      if (wave == 0)      { node = rr; m = 0; }
      else if (wave == 1) { node = rr / 3; m = 1 + rr % 3; }
      else                { int g = (wave - 2) * 16 + rr; node = g / 5; m = 4 + g % 5; }
      size_t obase = ((size_t)(blockIdx.x * 4 + node) * MTOT + m) * CH + c16;
      #pragma unroll
      for (int ct = 0; ct < 8; ++ct) {
        float v = acc[ct][i];
        if (wave == 0) v += bias[ct * 16 + c16];
        out[obase + ct * 16] = v * scale;
      }
    }
  }
}

extern "C" void kernel_launch(void* const* d_in, const int* in_sizes, int n_in,
                              void* d_out, int out_size, void* d_ws, size_t ws_size,
                              hipStream_t stream) {
  (void)in_sizes; (void)n_in; (void)out_size; (void)ws_size;
  const float* pos     = (const float*)d_in[0];
  const float* exp_pos = (const float*)d_in[1];
  // d_in[2] = h : unused by the reference computation
  const float* exp_h   = (const float*)d_in[3];
  const float* alpha   = (const float*)d_in[4];
  const int*   idx     = (const int*)d_in[5];
  const float* w1w     = (const float*)d_in[6];
  const float* w1b     = (const float*)d_in[7];
  const float* w2w     = (const float*)d_in[8];
  const float* w2b     = (const float*)d_in[9];
  const float* tpw     = (const float*)d_in[10];
  float* out = (float*)d_out;

  unsigned short* eh1T = (unsigned short*)d_ws;                 // bf16 [4096*1536] transposed
  unsigned short* w1s  = eh1T + (size_t)NN * 1536;              // bf16 swizzled [3*16384]
  unsigned short* w2s  = w1s + 3 * 16384;                       // bf16 swizzled [3*16384]

  wprep<<<48, 256, 0, stream>>>(w1w, w2w, w1s, w2s);
  so3lin_mfma<0, 1, 0><<<576, 256, 0, stream>>>(exp_h, w1s, w1b, eh1T);
  agg_tp_w2<<<NN / 4, 256, 0, stream>>>(eh1T, pos, exp_pos, alpha, idx, tpw, w2s, w2b, out);
}

// Round 4
// 150.640 us; speedup vs baseline: 1.0267x; 1.0267x over previous
//
#include <hip/hip_runtime.h>

#define NN 4096
#define MTOT 9
#define CH 128

// -------- Wigner-3j / TP constants (verified correct in earlier passes) ----
#define S3f 0.57735026918962576f   // 1/sqrt(3)
#define S2f 0.70710678118654752f   // 1/sqrt(2)
#define CUf 0.54772255750516611f   // sqrt(3/10)
#define CVf 0.31622776601683794f   // sqrt(1/10)
#define CWf 0.63245553203367587f   // 2/sqrt(10)
#define CAf 0.40824829046386302f   // 1/sqrt(6)
#define CA2f 0.81649658092772603f  // 2/sqrt(6)
#define YSf ((float)(2.04665350914 * 0.48860251190291992))

typedef __attribute__((ext_vector_type(8))) short short8;
typedef __attribute__((ext_vector_type(4))) float f32x4;
typedef __attribute__((ext_vector_type(2))) float f32x2;

__device__ __forceinline__ unsigned short f2b(float f) {
  unsigned u = __builtin_bit_cast(unsigned, f);
  u += 0x7FFFu + ((u >> 16) & 1u);           // RNE
  return (unsigned short)(u >> 16);
}

// ---------------- W pre-swizzle: fp32 [3,128,128] -> bf16 frag-order -------
// out[l*16384 + (((n>>4)*16 + kq)*16 + (n&15))*8 + j] = W[l][kq*8+j][n]
__global__ __launch_bounds__(256) void wprep(
    const float* __restrict__ w1, const float* __restrict__ w2,
    unsigned short* __restrict__ o1, unsigned short* __restrict__ o2)
{
  int g = blockIdx.x * 256 + threadIdx.x;    // 12288 total
  const float* W = w1;
  unsigned short* O = o1;
  int r = g;
  if (r >= 6144) { r -= 6144; W = w2; O = o2; }
  int l  = r >> 11;          // 2048 per l
  int r2 = r & 2047;
  int n  = r2 >> 4;
  int kq = r2 & 15;
  const float* src = W + l * 16384 + kq * 8 * CH + n;
  short8 v;
  #pragma unroll
  for (int j = 0; j < 8; ++j) v[j] = (short)f2b(src[j * CH]);
  *(short8*)(O + (size_t)l * 16384 + (((n >> 4) * 16 + kq) * 16 + (n & 15)) * 8) = v;
}

// ---------------- so3_linear via MFMA 16x16x32 bf16 (R1-verified) ----------
template <int XBF, int YBF, int NORM>
__global__ __launch_bounds__(256) void so3lin_mfma(
    const void* __restrict__ Xv, const unsigned short* __restrict__ Wsw,
    const float* __restrict__ bias, void* __restrict__ Yv)
{
  __shared__ unsigned short Bs[16384];   // 32 KB frag-order bf16 W_l
  const int bid = blockIdx.x;
  int l, blk0, m0, nm;
  if (bid < 64)       { l = 0; blk0 = bid;       m0 = 0; nm = 1; }
  else if (bid < 256) { l = 1; blk0 = bid - 64;  m0 = 1; nm = 3; }
  else                { l = 2; blk0 = bid - 256; m0 = 4; nm = 5; }
  const int t = threadIdx.x;

  {
    const float4* src = (const float4*)(Wsw + (size_t)l * 16384);
    float4* dst = (float4*)Bs;
    #pragma unroll
    for (int i = 0; i < 8; ++i) dst[t + i * 256] = src[t + i * 256];
  }
  __syncthreads();

  const int lane = t & 63;
  const int wave = t >> 6;
  const int c16  = lane & 15;
  const int quad = lane >> 4;
  const int rb   = (blk0 * 4 + wave) * 16;

  const int ra = rb + c16;
  const int nodeA = ra / nm;
  const int mA = m0 + (ra - nodeA * nm);
  const size_t abase = ((size_t)nodeA * MTOT + mA) * CH + quad * 8;

  f32x4 acc[8] = {};
  #pragma unroll
  for (int kk = 0; kk < CH; kk += 32) {
    short8 afrag;
    if (XBF) {
      afrag = *(const short8*)((const unsigned short*)Xv + abase + kk);
    } else {
      const float* xp = (const float*)Xv + abase + kk;
      float4 f0 = *(const float4*)xp;
      float4 f1 = *(const float4*)(xp + 4);
      afrag = (short8){(short)f2b(f0.x), (short)f2b(f0.y), (short)f2b(f0.z), (short)f2b(f0.w),
                       (short)f2b(f1.x), (short)f2b(f1.y), (short)f2b(f1.z), (short)f2b(f1.w)};
    }
    const int kq = (kk >> 3) + quad;
    #pragma unroll
    for (int ct = 0; ct < 8; ++ct) {
      short8 bfrag = *(const short8*)&Bs[((ct * 16 + kq) * 16 + c16) * 8];
      acc[ct] = __builtin_amdgcn_mfma_f32_16x16x32_bf16(afrag, bfrag, acc[ct], 0, 0, 0);
    }
  }

  const float scale = NORM ? (l == 0 ? 1.0f : (l == 1 ? S3f : S2f)) : 1.0f;
  #pragma unroll
  for (int i = 0; i < 4; ++i) {
    int r2 = rb + quad * 4 + i;
    int node2 = r2 / nm;
    int m2 = m0 + (r2 - node2 * nm);
    size_t obase = ((size_t)node2 * MTOT + m2) * CH + c16;
    #pragma unroll
    for (int ct = 0; ct < 8; ++ct) {
      float v = acc[ct][i];
      if (l == 0) v += bias[ct * 16 + c16];
      v *= scale;
      if (YBF) ((unsigned short*)Yv)[obase + ct * 16] = f2b(v);
      else     ((float*)Yv)[obase + ct * 16] = v;
    }
  }
}

// ------- gather + aggregate + fused TP + fused W2 linear (MFMA) ------------
// R1-verified structure, neighbor-split across wave pairs:
//   block = 512 thr = 8 waves = 4 nodes; wave (n4, half) gathers neighbors
//   half*8 .. half*8+7 with R1's dense scalar-dword loads (unchanged code).
//   Partial moments reduced exactly in f32 via LDS (2 m-phases, 40 KB).
//   TP + At staging: primary half-waves, R1 code with wave->n4.
//   W2 MFMA: all 8 waves, each tile's 8 ct-columns split ctb=half*4.
#define PADK 136   // row stride in shorts: 272 B, multiple of 16 for b128
__global__ __launch_bounds__(512) void agg_tp_w2(
    const unsigned short* __restrict__ X,   // eh1 bf16 [NN,9,128]
    const float* __restrict__ pos,
    const float* __restrict__ exp_pos,
    const float* __restrict__ alpha,
    const int*   __restrict__ idx,
    const float* __restrict__ tpw,
    const unsigned short* __restrict__ Wsw, // w2s swizzled bf16 [3*16384]
    const float* __restrict__ bias,         // w2b [128]
    float* __restrict__ out)                // fp32 [NN,9,128]
{
  __shared__ int   sIdx[4][16];
  __shared__ float sAl[4][128];
  __shared__ float sEy[4][48];
  __shared__ float sY[4][4];
  // union: moment-exchange buffer (4 nodes x 4 sets x 5 m x 64 lanes f32x2
  //        = 40960 B) reused afterwards as the 4 MFMA A-tiles (17408 B)
  __shared__ __align__(16) char UU[40960];
  float* mom = (float*)UU;
  unsigned short* At = (unsigned short*)UU;

  const int t = threadIdx.x, wave = t >> 6, lane = t & 63;
  const int n4 = wave & 3, half = wave >> 2;
  const int b = blockIdx.x * 4 + n4;

  if (half == 0) {
    if (lane < 16) sIdx[n4][lane] = idx[b * 16 + lane];
    sAl[n4][lane]      = alpha[b * 128 + lane];
    sAl[n4][lane + 64] = alpha[b * 128 + lane + 64];
    if (lane < 3) sY[n4][lane] = YSf * pos[b * 3 + lane];
  }
  __syncthreads();
  if (half == 0 && lane < 48) {
    int j = lane / 3, cmp = lane - 3 * j;
    sEy[n4][lane] = YSf * exp_pos[sIdx[n4][j] * 3 + cmp];
  }
  __syncthreads();

  const int h = lane >> 3;
  const int c0 = lane * 2;
  f32x2 A0[9] = {}, A1[9] = {}, A2[9] = {}, A3[9] = {};
  #pragma unroll 2
  for (int jj = 0; jj < 8; ++jj) {
    const int j = half * 8 + jj;
    float al = sAl[n4][j * 8 + h];
    float e0 = al * sEy[n4][j * 3 + 0];
    float e1 = al * sEy[n4][j * 3 + 1];
    float e2 = al * sEy[n4][j * 3 + 2];
    f32x2 alv = {al, al};
    f32x2 e0v = {e0, e0};
    f32x2 e1v = {e1, e1};
    f32x2 e2v = {e2, e2};
    const unsigned short* xp = X + (size_t)sIdx[n4][j] * (MTOT * CH) + c0;
    #pragma unroll
    for (int m = 0; m < 9; ++m) {
      unsigned v = *(const unsigned*)(xp + m * CH);
      f32x2 x;
      x.x = __builtin_bit_cast(float, v << 16);
      x.y = __builtin_bit_cast(float, v & 0xFFFF0000u);
      A0[m] += alv * x; A1[m] += e0v * x; A2[m] += e1v * x; A3[m] += e2v * x;
    }
  }

  // ---- exact f32 moment reduction across the wave pair (2 m-phases) ----
  // row index: ((n4*4 + set)*5 + dm)*64 + lane  (f32x2 units)
  #pragma unroll
  for (int ph = 0; ph < 2; ++ph) {
    const int m0p = ph ? 5 : 0;
    const int nmp = ph ? 4 : 5;
    if (half == 1) {
      #pragma unroll
      for (int dm = 0; dm < nmp; ++dm) {
        *(f32x2*)&mom[2 * ((((n4 * 4 + 0) * 5) + dm) * 64 + lane)] = A0[m0p + dm];
        *(f32x2*)&mom[2 * ((((n4 * 4 + 1) * 5) + dm) * 64 + lane)] = A1[m0p + dm];
        *(f32x2*)&mom[2 * ((((n4 * 4 + 2) * 5) + dm) * 64 + lane)] = A2[m0p + dm];
        *(f32x2*)&mom[2 * ((((n4 * 4 + 3) * 5) + dm) * 64 + lane)] = A3[m0p + dm];
      }
    }
    __syncthreads();
    if (half == 0) {
      #pragma unroll
      for (int dm = 0; dm < nmp; ++dm) {
        A0[m0p + dm] += *(const f32x2*)&mom[2 * ((((n4 * 4 + 0) * 5) + dm) * 64 + lane)];
        A1[m0p + dm] += *(const f32x2*)&mom[2 * ((((n4 * 4 + 1) * 5) + dm) * 64 + lane)];
        A2[m0p + dm] += *(const f32x2*)&mom[2 * ((((n4 * 4 + 2) * 5) + dm) * 64 + lane)];
        A3[m0p + dm] += *(const f32x2*)&mom[2 * ((((n4 * 4 + 3) * 5) + dm) * 64 + lane)];
      }
    }
    __syncthreads();
  }

  if (half == 0) {
    const float y0 = sY[n4][0], yv1 = sY[n4][1], y2 = sY[n4][2];
    float OUT[9][2];
    #pragma unroll
    for (int ch = 0; ch < 2; ++ch) {
      const int c = c0 + ch;
      const float w0 = tpw[c], w1 = tpw[CH + c], w2 = tpw[2 * CH + c];
      const float w3 = tpw[3 * CH + c], w4 = tpw[4 * CH + c], w5 = tpw[5 * CH + c];
      const float x0 = A0[0][ch];
      const float p0 = A0[1][ch], p1 = A0[2][ch], p2 = A0[3][ch];
      const float d0 = A0[4][ch], d1 = A0[5][ch], d2 = A0[6][ch], d3 = A0[7][ch], d4 = A0[8][ch];

      float r0 = w1 * S3f * (p0 * y0 + p1 * yv1 + p2 * y2);
      float r1 = w0 * x0 * y0 + w2 * S2f * (p1 * y2 - p2 * yv1)
               + w4 * (CUf * (d0 * y2 + d1 * yv1 - d4 * y0) - CVf * d2 * y0);
      float r2 = w0 * x0 * yv1 + w2 * S2f * (p2 * y0 - p0 * y2)
               + w4 * (CUf * (d1 * y0 + d3 * y2) + CWf * d2 * yv1);
      float r3 = w0 * x0 * y2 + w2 * S2f * (p0 * yv1 - p1 * y0)
               + w4 * (CUf * (d0 * y0 + d4 * y2 + d3 * yv1) - CVf * d2 * y2);
      float r4 = w3 * S2f * (p0 * y2 + p2 * y0)
               + w5 * (CAf * (d3 * y2 - d1 * y0) - 2.f * CAf * d4 * yv1);
      float r5 = w3 * S2f * (p0 * yv1 + p1 * y0)
               + w5 * (CAf * (d0 * y0 - d3 * yv1 + d4 * y2) + S2f * d2 * y2);
      float r6 = w3 * (CA2f * p1 * yv1 - CAf * (p0 * y0 + p2 * y2))
               + w5 * S2f * (d3 * y0 - d1 * y2);
      float r7 = w3 * S2f * (p1 * y2 + p2 * yv1)
               + w5 * (CAf * (d1 * yv1 - d0 * y2 + d4 * y0) - S2f * d2 * y0);
      float r8 = w3 * S2f * (p2 * y2 - p0 * y0)
               + w5 * CAf * (2.f * d0 * yv1 - d1 * y2 - d3 * y0);

      float q0 = w1 * S3f * (A1[1][ch] + A2[2][ch] + A3[3][ch]);
      float q1 = w0 * A1[0][ch] + w2 * S2f * (A3[2][ch] - A2[3][ch])
               + w4 * (CUf * (A3[4][ch] + A2[5][ch] - A1[8][ch]) - CVf * A1[6][ch]);
      float q2 = w0 * A2[0][ch] + w2 * S2f * (A1[3][ch] - A3[1][ch])
               + w4 * (CUf * (A1[5][ch] + A3[7][ch]) + CWf * A2[6][ch]);
      float q3 = w0 * A3[0][ch] + w2 * S2f * (A2[1][ch] - A1[2][ch])
               + w4 * (CUf * (A1[4][ch] + A3[8][ch] + A2[7][ch]) - CVf * A3[6][ch]);
      float q4 = w3 * S2f * (A3[1][ch] + A1[3][ch])
               + w5 * (CAf * (A3[7][ch] - A1[5][ch]) - 2.f * CAf * A2[8][ch]);
      float q5 = w3 * S2f * (A2[1][ch] + A1[2][ch])
               + w5 * (CAf * (A1[4][ch] - A2[7][ch] + A3[8][ch]) + S2f * A3[6][ch]);
      float q6 = w3 * (CA2f * A2[2][ch] - CAf * (A1[1][ch] + A3[3][ch]))
               + w5 * S2f * (A1[7][ch] - A3[5][ch]);
      float q7 = w3 * S2f * (A3[2][ch] + A2[3][ch])
               + w5 * (CAf * (A2[5][ch] - A3[4][ch] + A1[8][ch]) - S2f * A1[6][ch]);
      float q8 = w3 * S2f * (A3[3][ch] - A1[1][ch])
               + w5 * CAf * (2.f * A2[4][ch] - A3[5][ch] - A1[7][ch]);

      OUT[0][ch] = r0 - q0; OUT[1][ch] = r1 - q1; OUT[2][ch] = r2 - q2;
      OUT[3][ch] = r3 - q3; OUT[4][ch] = r4 - q4; OUT[5][ch] = r5 - q5;
      OUT[6][ch] = r6 - q6; OUT[7][ch] = r7 - q7; OUT[8][ch] = r8 - q8;
    }

    // ---- stage dif rows (bf16, packed dwords) into A-frag tiles ----
    // row map (R1): m=0 -> tile0 row n4 ; m=1..3 -> tile1 row n4*3+(m-1)
    //               m=4..8 -> g=n4*5+(m-4): tile 2+(g>>4), row g&15
    #pragma unroll
    for (int m = 0; m < 9; ++m) {
      int tt, rr;
      if (m == 0)      { tt = 0; rr = n4; }
      else if (m < 4)  { tt = 1; rr = n4 * 3 + (m - 1); }
      else             { int g = n4 * 5 + (m - 4); tt = 2 + (g >> 4); rr = g & 15; }
      unsigned dw = (unsigned)f2b(OUT[m][0]) | ((unsigned)f2b(OUT[m][1]) << 16);
      *(unsigned*)&At[(tt * 16 + rr) * PADK + c0] = dw;
    }
  }
  __syncthreads();

  // ---- W2 MFMA phase: tile by (wave&3), ct-columns split by half ----
  const int c16  = lane & 15;
  const int quad = lane >> 4;
  const int tw   = wave & 3;
  const int ctb  = half * 4;
  const int l2i  = (tw == 0) ? 0 : (tw == 1 ? 1 : 2);
  const unsigned short* Wl = Wsw + (size_t)l2i * 16384;

  f32x4 acc[4] = {};
  #pragma unroll
  for (int kk = 0; kk < CH; kk += 32) {
    short8 afrag = *(const short8*)&At[(tw * 16 + c16) * PADK + quad * 8 + kk];
    const int kq = (kk >> 3) + quad;
    #pragma unroll
    for (int ct = 0; ct < 4; ++ct) {
      short8 bfrag = *(const short8*)&Wl[(((ctb + ct) * 16 + kq) * 16 + c16) * 8];
      acc[ct] = __builtin_amdgcn_mfma_f32_16x16x32_bf16(afrag, bfrag, acc[ct], 0, 0, 0);
    }
  }

  const float scale = (tw == 0) ? 1.0f : (tw == 1 ? S3f : S2f);
  const int rmax = (tw == 1) ? 12 : ((tw == 2) ? 16 : 4);
  #pragma unroll
  for (int i = 0; i < 4; ++i) {
    int rr = quad * 4 + i;
    if (rr < rmax) {
      int node, m;
      if (tw == 0)      { node = rr; m = 0; }
      else if (tw == 1) { node = rr / 3; m = 1 + rr % 3; }
      else              { int g = (tw - 2) * 16 + rr; node = g / 5; m = 4 + g % 5; }
      size_t obase = ((size_t)(blockIdx.x * 4 + node) * MTOT + m) * CH + c16;
      #pragma unroll
      for (int ct = 0; ct < 4; ++ct) {
        float v = acc[ct][i];
        if (tw == 0) v += bias[(ctb + ct) * 16 + c16];
        out[obase + (ctb + ct) * 16] = v * scale;
      }
    }
  }
}

extern "C" void kernel_launch(void* const* d_in, const int* in_sizes, int n_in,
                              void* d_out, int out_size, void* d_ws, size_t ws_size,
                              hipStream_t stream) {
  (void)in_sizes; (void)n_in; (void)out_size; (void)ws_size;
  const float* pos     = (const float*)d_in[0];
  const float* exp_pos = (const float*)d_in[1];
  // d_in[2] = h : unused by the reference computation
  const float* exp_h   = (const float*)d_in[3];
  const float* alpha   = (const float*)d_in[4];
  const int*   idx     = (const int*)d_in[5];
  const float* w1w     = (const float*)d_in[6];
  const float* w1b     = (const float*)d_in[7];
  const float* w2w     = (const float*)d_in[8];
  const float* w2b     = (const float*)d_in[9];
  const float* tpw     = (const float*)d_in[10];
  float* out = (float*)d_out;

  unsigned short* eh1 = (unsigned short*)d_ws;                  // bf16 [4096*9*128]
  unsigned short* w1s = eh1 + (size_t)NN * MTOT * CH;           // bf16 swizzled [3*16384]
  unsigned short* w2s = w1s + 3 * 16384;                        // bf16 swizzled [3*16384]

  wprep<<<48, 256, 0, stream>>>(w1w, w2w, w1s, w2s);
  so3lin_mfma<0, 1, 0><<<576, 256, 0, stream>>>(exp_h, w1s, w1b, eh1);
  agg_tp_w2<<<NN / 4, 512, 0, stream>>>(eh1, pos, exp_pos, alpha, idx, tpw, w2s, w2b, out);
}

// Round 5
// 140.306 us; speedup vs baseline: 1.1023x; 1.0737x over previous
//
#include <hip/hip_runtime.h>

#define NN 4096
#define MTOT 9
#define CH 128

// -------- Wigner-3j / TP constants (verified correct in earlier passes) ----
#define S3f 0.57735026918962576f   // 1/sqrt(3)
#define S2f 0.70710678118654752f   // 1/sqrt(2)
#define CUf 0.54772255750516611f   // sqrt(3/10)
#define CVf 0.31622776601683794f   // sqrt(1/10)
#define CWf 0.63245553203367587f   // 2/sqrt(10)
#define CAf 0.40824829046386302f   // 1/sqrt(6)
#define CA2f 0.81649658092772603f  // 2/sqrt(6)
#define YSf ((float)(2.04665350914 * 0.48860251190291992))

typedef __attribute__((ext_vector_type(8))) short short8;
typedef __attribute__((ext_vector_type(4))) float f32x4;
typedef __attribute__((ext_vector_type(2))) float f32x2;

__device__ __forceinline__ unsigned short f2b(float f) {
  unsigned u = __builtin_bit_cast(unsigned, f);
  u += 0x7FFFu + ((u >> 16) & 1u);           // RNE
  return (unsigned short)(u >> 16);
}

// ---------------- W pre-swizzle: fp32 [3,128,128] -> bf16 frag-order -------
// out[l*16384 + (((n>>4)*16 + kq)*16 + (n&15))*8 + j] = W[l][kq*8+j][n]
__global__ __launch_bounds__(256) void wprep(
    const float* __restrict__ w1, const float* __restrict__ w2,
    unsigned short* __restrict__ o1, unsigned short* __restrict__ o2)
{
  int g = blockIdx.x * 256 + threadIdx.x;    // 12288 total
  const float* W = w1;
  unsigned short* O = o1;
  int r = g;
  if (r >= 6144) { r -= 6144; W = w2; O = o2; }
  int l  = r >> 11;          // 2048 per l
  int r2 = r & 2047;
  int n  = r2 >> 4;
  int kq = r2 & 15;
  const float* src = W + l * 16384 + kq * 8 * CH + n;
  short8 v;
  #pragma unroll
  for (int j = 0; j < 8; ++j) v[j] = (short)f2b(src[j * CH]);
  *(short8*)(O + (size_t)l * 16384 + (((n >> 4) * 16 + kq) * 16 + (n & 15)) * 8) = v;
}

// ---------------- so3_linear via MFMA 16x16x32 bf16 (R1-verified) ----------
template <int XBF, int YBF, int NORM>
__global__ __launch_bounds__(256) void so3lin_mfma(
    const void* __restrict__ Xv, const unsigned short* __restrict__ Wsw,
    const float* __restrict__ bias, void* __restrict__ Yv)
{
  __shared__ unsigned short Bs[16384];   // 32 KB frag-order bf16 W_l
  const int bid = blockIdx.x;
  int l, blk0, m0, nm;
  if (bid < 64)       { l = 0; blk0 = bid;       m0 = 0; nm = 1; }
  else if (bid < 256) { l = 1; blk0 = bid - 64;  m0 = 1; nm = 3; }
  else                { l = 2; blk0 = bid - 256; m0 = 4; nm = 5; }
  const int t = threadIdx.x;

  {
    const float4* src = (const float4*)(Wsw + (size_t)l * 16384);
    float4* dst = (float4*)Bs;
    #pragma unroll
    for (int i = 0; i < 8; ++i) dst[t + i * 256] = src[t + i * 256];
  }
  __syncthreads();

  const int lane = t & 63;
  const int wave = t >> 6;
  const int c16  = lane & 15;
  const int quad = lane >> 4;
  const int rb   = (blk0 * 4 + wave) * 16;

  const int ra = rb + c16;
  const int nodeA = ra / nm;
  const int mA = m0 + (ra - nodeA * nm);
  const size_t abase = ((size_t)nodeA * MTOT + mA) * CH + quad * 8;

  f32x4 acc[8] = {};
  #pragma unroll
  for (int kk = 0; kk < CH; kk += 32) {
    short8 afrag;
    if (XBF) {
      afrag = *(const short8*)((const unsigned short*)Xv + abase + kk);
    } else {
      const float* xp = (const float*)Xv + abase + kk;
      float4 f0 = *(const float4*)xp;
      float4 f1 = *(const float4*)(xp + 4);
      afrag = (short8){(short)f2b(f0.x), (short)f2b(f0.y), (short)f2b(f0.z), (short)f2b(f0.w),
                       (short)f2b(f1.x), (short)f2b(f1.y), (short)f2b(f1.z), (short)f2b(f1.w)};
    }
    const int kq = (kk >> 3) + quad;
    #pragma unroll
    for (int ct = 0; ct < 8; ++ct) {
      short8 bfrag = *(const short8*)&Bs[((ct * 16 + kq) * 16 + c16) * 8];
      acc[ct] = __builtin_amdgcn_mfma_f32_16x16x32_bf16(afrag, bfrag, acc[ct], 0, 0, 0);
    }
  }

  const float scale = NORM ? (l == 0 ? 1.0f : (l == 1 ? S3f : S2f)) : 1.0f;
  #pragma unroll
  for (int i = 0; i < 4; ++i) {
    int r2 = rb + quad * 4 + i;
    int node2 = r2 / nm;
    int m2 = m0 + (r2 - node2 * nm);
    size_t obase = ((size_t)node2 * MTOT + m2) * CH + c16;
    #pragma unroll
    for (int ct = 0; ct < 8; ++ct) {
      float v = acc[ct][i];
      if (l == 0) v += bias[ct * 16 + c16];
      v *= scale;
      if (YBF) ((unsigned short*)Yv)[obase + ct * 16] = f2b(v);
      else     ((float*)Yv)[obase + ct * 16] = v;
    }
  }
}

// ------- gather + 4-way aggregate + fused TP + fused W2 linear (MFMA) ------
// EXACT Round-1 verified structure (4 waves = 4 nodes/block, 256 thr).
// Single change: neighbors visited in idx-QUARTILE order (4-ballot rank sort
// into sPerm) so all blocks sweep the 9.4 MB table in 4 loose phases of
// ~2.35 MB each -> phase working set fits the 4 MB per-XCD L2.
// fp32 sum reorder only (commutative up to rounding; threshold has 4x slack).
#define PADK 136   // row stride in shorts: 272 B, multiple of 16 for b128
__global__ __launch_bounds__(256) void agg_tp_w2(
    const unsigned short* __restrict__ X,   // eh1 bf16 [NN,9,128]
    const float* __restrict__ pos,
    const float* __restrict__ exp_pos,
    const float* __restrict__ alpha,
    const int*   __restrict__ idx,
    const float* __restrict__ tpw,
    const unsigned short* __restrict__ Wsw, // w2s swizzled bf16 [3*16384]
    const float* __restrict__ bias,         // w2b [128]
    float* __restrict__ out)                // fp32 [NN,9,128]
{
  __shared__ int   sIdx[4][16];
  __shared__ float sAl[4][128];
  __shared__ float sEy[4][48];
  __shared__ float sY[4][4];
  __shared__ unsigned char sPerm[4][16];
  __shared__ __align__(16) unsigned short At[4 * 16 * PADK];  // 17 KB dif tiles
  const int t = threadIdx.x, wave = t >> 6, lane = t & 63;
  const int b = blockIdx.x * 4 + wave;

  if (lane < 16) sIdx[wave][lane] = idx[b * 16 + lane];
  sAl[wave][lane]      = alpha[b * 128 + lane];
  sAl[wave][lane + 64] = alpha[b * 128 + lane + 64];
  if (lane < 3) sY[wave][lane] = YSf * pos[b * 3 + lane];
  __syncthreads();
  if (lane < 48) {
    int j = lane / 3, cmp = lane - 3 * j;
    sEy[wave][lane] = YSf * exp_pos[sIdx[wave][j] * 3 + cmp];
  }

  // ---- bucket-rank sort of the 16 neighbors by idx quartile ----
  {
    int key = (lane < 16) ? (sIdx[wave][lane] >> 10) : 7;   // 0..3 valid
    unsigned m0 = (unsigned)__ballot(key == 0) & 0xFFFFu;
    unsigned m1 = (unsigned)__ballot(key == 1) & 0xFFFFu;
    unsigned m2 = (unsigned)__ballot(key == 2) & 0xFFFFu;
    unsigned m3 = (unsigned)__ballot(key == 3) & 0xFFFFu;
    if (lane < 16) {
      unsigned below = (1u << lane) - 1u;
      int pos;
      if (key == 0)      pos = __popc(m0 & below);
      else if (key == 1) pos = __popc(m0) + __popc(m1 & below);
      else if (key == 2) pos = __popc(m0) + __popc(m1) + __popc(m2 & below);
      else               pos = __popc(m0) + __popc(m1) + __popc(m2) + __popc(m3 & below);
      sPerm[wave][pos] = (unsigned char)lane;
    }
  }
  __syncthreads();

  const int h = lane >> 3;
  const int c0 = lane * 2;
  f32x2 A0[9] = {}, A1[9] = {}, A2[9] = {}, A3[9] = {};
  #pragma unroll 2
  for (int jj = 0; jj < 16; ++jj) {
    const int j = sPerm[wave][jj];
    float al = sAl[wave][j * 8 + h];
    float e0 = al * sEy[wave][j * 3 + 0];
    float e1 = al * sEy[wave][j * 3 + 1];
    float e2 = al * sEy[wave][j * 3 + 2];
    f32x2 alv = {al, al};
    f32x2 e0v = {e0, e0};
    f32x2 e1v = {e1, e1};
    f32x2 e2v = {e2, e2};
    const unsigned short* xp = X + (size_t)sIdx[wave][j] * (MTOT * CH) + c0;
    #pragma unroll
    for (int m = 0; m < 9; ++m) {
      unsigned v = *(const unsigned*)(xp + m * CH);
      f32x2 x;
      x.x = __builtin_bit_cast(float, v << 16);
      x.y = __builtin_bit_cast(float, v & 0xFFFF0000u);
      A0[m] += alv * x; A1[m] += e0v * x; A2[m] += e1v * x; A3[m] += e2v * x;
    }
  }

  const float y0 = sY[wave][0], yv1 = sY[wave][1], y2 = sY[wave][2];
  float OUT[9][2];
  #pragma unroll
  for (int ch = 0; ch < 2; ++ch) {
    const int c = c0 + ch;
    const float w0 = tpw[c], w1 = tpw[CH + c], w2 = tpw[2 * CH + c];
    const float w3 = tpw[3 * CH + c], w4 = tpw[4 * CH + c], w5 = tpw[5 * CH + c];
    const float x0 = A0[0][ch];
    const float p0 = A0[1][ch], p1 = A0[2][ch], p2 = A0[3][ch];
    const float d0 = A0[4][ch], d1 = A0[5][ch], d2 = A0[6][ch], d3 = A0[7][ch], d4 = A0[8][ch];

    float r0 = w1 * S3f * (p0 * y0 + p1 * yv1 + p2 * y2);
    float r1 = w0 * x0 * y0 + w2 * S2f * (p1 * y2 - p2 * yv1)
             + w4 * (CUf * (d0 * y2 + d1 * yv1 - d4 * y0) - CVf * d2 * y0);
    float r2 = w0 * x0 * yv1 + w2 * S2f * (p2 * y0 - p0 * y2)
             + w4 * (CUf * (d1 * y0 + d3 * y2) + CWf * d2 * yv1);
    float r3 = w0 * x0 * y2 + w2 * S2f * (p0 * yv1 - p1 * y0)
             + w4 * (CUf * (d0 * y0 + d4 * y2 + d3 * yv1) - CVf * d2 * y2);
    float r4 = w3 * S2f * (p0 * y2 + p2 * y0)
             + w5 * (CAf * (d3 * y2 - d1 * y0) - 2.f * CAf * d4 * yv1);
    float r5 = w3 * S2f * (p0 * yv1 + p1 * y0)
             + w5 * (CAf * (d0 * y0 - d3 * yv1 + d4 * y2) + S2f * d2 * y2);
    float r6 = w3 * (CA2f * p1 * yv1 - CAf * (p0 * y0 + p2 * y2))
             + w5 * S2f * (d3 * y0 - d1 * y2);
    float r7 = w3 * S2f * (p1 * y2 + p2 * yv1)
             + w5 * (CAf * (d1 * yv1 - d0 * y2 + d4 * y0) - S2f * d2 * y0);
    float r8 = w3 * S2f * (p2 * y2 - p0 * y0)
             + w5 * CAf * (2.f * d0 * yv1 - d1 * y2 - d3 * y0);

    float q0 = w1 * S3f * (A1[1][ch] + A2[2][ch] + A3[3][ch]);
    float q1 = w0 * A1[0][ch] + w2 * S2f * (A3[2][ch] - A2[3][ch])
             + w4 * (CUf * (A3[4][ch] + A2[5][ch] - A1[8][ch]) - CVf * A1[6][ch]);
    float q2 = w0 * A2[0][ch] + w2 * S2f * (A1[3][ch] - A3[1][ch])
             + w4 * (CUf * (A1[5][ch] + A3[7][ch]) + CWf * A2[6][ch]);
    float q3 = w0 * A3[0][ch] + w2 * S2f * (A2[1][ch] - A1[2][ch])
             + w4 * (CUf * (A1[4][ch] + A3[8][ch] + A2[7][ch]) - CVf * A3[6][ch]);
    float q4 = w3 * S2f * (A3[1][ch] + A1[3][ch])
             + w5 * (CAf * (A3[7][ch] - A1[5][ch]) - 2.f * CAf * A2[8][ch]);
    float q5 = w3 * S2f * (A2[1][ch] + A1[2][ch])
             + w5 * (CAf * (A1[4][ch] - A2[7][ch] + A3[8][ch]) + S2f * A3[6][ch]);
    float q6 = w3 * (CA2f * A2[2][ch] - CAf * (A1[1][ch] + A3[3][ch]))
             + w5 * S2f * (A1[7][ch] - A3[5][ch]);
    float q7 = w3 * S2f * (A3[2][ch] + A2[3][ch])
             + w5 * (CAf * (A2[5][ch] - A3[4][ch] + A1[8][ch]) - S2f * A1[6][ch]);
    float q8 = w3 * S2f * (A3[3][ch] - A1[1][ch])
             + w5 * CAf * (2.f * A2[4][ch] - A3[5][ch] - A1[7][ch]);

    OUT[0][ch] = r0 - q0; OUT[1][ch] = r1 - q1; OUT[2][ch] = r2 - q2;
    OUT[3][ch] = r3 - q3; OUT[4][ch] = r4 - q4; OUT[5][ch] = r5 - q5;
    OUT[6][ch] = r6 - q6; OUT[7][ch] = r7 - q7; OUT[8][ch] = r8 - q8;
  }

  // ---- Phase 2: stage dif rows (bf16, packed dwords) into A-frag tiles ----
  // row map: m=0 -> tile0 row w ; m=1..3 -> tile1 row w*3+(m-1)
  //          m=4..8 -> g=w*5+(m-4): tile 2+(g>>4), row g&15
  #pragma unroll
  for (int m = 0; m < 9; ++m) {
    int tt, rr;
    if (m == 0)      { tt = 0; rr = wave; }
    else if (m < 4)  { tt = 1; rr = wave * 3 + (m - 1); }
    else             { int g = wave * 5 + (m - 4); tt = 2 + (g >> 4); rr = g & 15; }
    unsigned dw = (unsigned)f2b(OUT[m][0]) | ((unsigned)f2b(OUT[m][1]) << 16);
    *(unsigned*)&At[(tt * 16 + rr) * PADK + c0] = dw;
  }
  __syncthreads();

  // ---- Phase 3: per-wave MFMA tile against w2s fragments (global, L2-hot) -
  const int c16  = lane & 15;
  const int quad = lane >> 4;
  const int l2i  = (wave == 0) ? 0 : (wave == 1 ? 1 : 2);
  const unsigned short* Wl = Wsw + (size_t)l2i * 16384;

  f32x4 acc[8] = {};
  #pragma unroll
  for (int kk = 0; kk < CH; kk += 32) {
    short8 afrag = *(const short8*)&At[(wave * 16 + c16) * PADK + quad * 8 + kk];
    const int kq = (kk >> 3) + quad;
    #pragma unroll
    for (int ct = 0; ct < 8; ++ct) {
      short8 bfrag = *(const short8*)&Wl[((ct * 16 + kq) * 16 + c16) * 8];
      acc[ct] = __builtin_amdgcn_mfma_f32_16x16x32_bf16(afrag, bfrag, acc[ct], 0, 0, 0);
    }
  }

  // ---- Phase 4: bias (l0) + per-l scale, store fp32 ----
  const float scale = (wave == 0) ? 1.0f : (wave == 1 ? S3f : S2f);
  const int rmax = (wave == 1) ? 12 : ((wave == 2) ? 16 : 4);
  #pragma unroll
  for (int i = 0; i < 4; ++i) {
    int rr = quad * 4 + i;
    if (rr < rmax) {
      int node, m;
      if (wave == 0)      { node = rr; m = 0; }
      else if (wave == 1) { node = rr / 3; m = 1 + rr % 3; }
      else                { int g = (wave - 2) * 16 + rr; node = g / 5; m = 4 + g % 5; }
      size_t obase = ((size_t)(blockIdx.x * 4 + node) * MTOT + m) * CH + c16;
      #pragma unroll
      for (int ct = 0; ct < 8; ++ct) {
        float v = acc[ct][i];
        if (wave == 0) v += bias[ct * 16 + c16];
        out[obase + ct * 16] = v * scale;
      }
    }
  }
}

extern "C" void kernel_launch(void* const* d_in, const int* in_sizes, int n_in,
                              void* d_out, int out_size, void* d_ws, size_t ws_size,
                              hipStream_t stream) {
  (void)in_sizes; (void)n_in; (void)out_size; (void)ws_size;
  const float* pos     = (const float*)d_in[0];
  const float* exp_pos = (const float*)d_in[1];
  // d_in[2] = h : unused by the reference computation
  const float* exp_h   = (const float*)d_in[3];
  const float* alpha   = (const float*)d_in[4];
  const int*   idx     = (const int*)d_in[5];
  const float* w1w     = (const float*)d_in[6];
  const float* w1b     = (const float*)d_in[7];
  const float* w2w     = (const float*)d_in[8];
  const float* w2b     = (const float*)d_in[9];
  const float* tpw     = (const float*)d_in[10];
  float* out = (float*)d_out;

  unsigned short* eh1 = (unsigned short*)d_ws;                  // bf16 [4096*9*128]
  unsigned short* w1s = eh1 + (size_t)NN * MTOT * CH;           // bf16 swizzled [3*16384]
  unsigned short* w2s = w1s + 3 * 16384;                        // bf16 swizzled [3*16384]

  wprep<<<48, 256, 0, stream>>>(w1w, w2w, w1s, w2s);
  so3lin_mfma<0, 1, 0><<<576, 256, 0, stream>>>(exp_h, w1s, w1b, eh1);
  agg_tp_w2<<<NN / 4, 256, 0, stream>>>(eh1, pos, exp_pos, alpha, idx, tpw, w2s, w2b, out);
}

// Round 6
// 132.171 us; speedup vs baseline: 1.1701x; 1.0615x over previous
//
#include <hip/hip_runtime.h>

#define NN 4096
#define MTOT 9
#define CH 128

// -------- Wigner-3j / TP constants (verified correct in earlier passes) ----
#define S3f 0.57735026918962576f   // 1/sqrt(3)
#define S2f 0.70710678118654752f   // 1/sqrt(2)
#define CUf 0.54772255750516611f   // sqrt(3/10)
#define CVf 0.31622776601683794f   // sqrt(1/10)
#define CWf 0.63245553203367587f   // 2/sqrt(10)
#define CAf 0.40824829046386302f   // 1/sqrt(6)
#define CA2f 0.81649658092772603f  // 2/sqrt(6)
#define YSf ((float)(2.04665350914 * 0.48860251190291992))

typedef __attribute__((ext_vector_type(8))) short short8;
typedef __attribute__((ext_vector_type(4))) float f32x4;
typedef __attribute__((ext_vector_type(2))) float f32x2;

__device__ __forceinline__ unsigned short f2b(float f) {
  unsigned u = __builtin_bit_cast(unsigned, f);
  u += 0x7FFFu + ((u >> 16) & 1u);           // RNE
  return (unsigned short)(u >> 16);
}

// ---------------- W pre-swizzle: fp32 [3,128,128] -> bf16 frag-order -------
// out[l*16384 + (((n>>4)*16 + kq)*16 + (n&15))*8 + j] = W[l][kq*8+j][n]
__global__ __launch_bounds__(256) void wprep(
    const float* __restrict__ w1, const float* __restrict__ w2,
    unsigned short* __restrict__ o1, unsigned short* __restrict__ o2)
{
  int g = blockIdx.x * 256 + threadIdx.x;    // 12288 total
  const float* W = w1;
  unsigned short* O = o1;
  int r = g;
  if (r >= 6144) { r -= 6144; W = w2; O = o2; }
  int l  = r >> 11;          // 2048 per l
  int r2 = r & 2047;
  int n  = r2 >> 4;
  int kq = r2 & 15;
  const float* src = W + l * 16384 + kq * 8 * CH + n;
  short8 v;
  #pragma unroll
  for (int j = 0; j < 8; ++j) v[j] = (short)f2b(src[j * CH]);
  *(short8*)(O + (size_t)l * 16384 + (((n >> 4) * 16 + kq) * 16 + (n & 15)) * 8) = v;
}

// ---------------- so3_linear via MFMA 16x16x32 bf16 ----------------
// W arrives pre-swizzled bf16; staging is 8 contiguous dwordx4 + b128 writes.
template <int XBF, int YBF, int NORM>
__global__ __launch_bounds__(256) void so3lin_mfma(
    const void* __restrict__ Xv, const unsigned short* __restrict__ Wsw,
    const float* __restrict__ bias, void* __restrict__ Yv)
{
  __shared__ unsigned short Bs[16384];   // 32 KB frag-order bf16 W_l
  const int bid = blockIdx.x;
  int l, blk0, m0, nm;
  if (bid < 64)       { l = 0; blk0 = bid;       m0 = 0; nm = 1; }
  else if (bid < 256) { l = 1; blk0 = bid - 64;  m0 = 1; nm = 3; }
  else                { l = 2; blk0 = bid - 256; m0 = 4; nm = 5; }
  const int t = threadIdx.x;

  {
    const float4* src = (const float4*)(Wsw + (size_t)l * 16384);
    float4* dst = (float4*)Bs;
    #pragma unroll
    for (int i = 0; i < 8; ++i) dst[t + i * 256] = src[t + i * 256];
  }
  __syncthreads();

  const int lane = t & 63;
  const int wave = t >> 6;
  const int c16  = lane & 15;
  const int quad = lane >> 4;
  const int rb   = (blk0 * 4 + wave) * 16;

  const int ra = rb + c16;
  const int nodeA = ra / nm;
  const int mA = m0 + (ra - nodeA * nm);
  const size_t abase = ((size_t)nodeA * MTOT + mA) * CH + quad * 8;

  f32x4 acc[8] = {};
  #pragma unroll
  for (int kk = 0; kk < CH; kk += 32) {
    short8 afrag;
    if (XBF) {
      afrag = *(const short8*)((const unsigned short*)Xv + abase + kk);
    } else {
      const float* xp = (const float*)Xv + abase + kk;
      float4 f0 = *(const float4*)xp;
      float4 f1 = *(const float4*)(xp + 4);
      afrag = (short8){(short)f2b(f0.x), (short)f2b(f0.y), (short)f2b(f0.z), (short)f2b(f0.w),
                       (short)f2b(f1.x), (short)f2b(f1.y), (short)f2b(f1.z), (short)f2b(f1.w)};
    }
    const int kq = (kk >> 3) + quad;
    #pragma unroll
    for (int ct = 0; ct < 8; ++ct) {
      short8 bfrag = *(const short8*)&Bs[((ct * 16 + kq) * 16 + c16) * 8];
      acc[ct] = __builtin_amdgcn_mfma_f32_16x16x32_bf16(afrag, bfrag, acc[ct], 0, 0, 0);
    }
  }

  const float scale = NORM ? (l == 0 ? 1.0f : (l == 1 ? S3f : S2f)) : 1.0f;
  #pragma unroll
  for (int i = 0; i < 4; ++i) {
    int r2 = rb + quad * 4 + i;
    int node2 = r2 / nm;
    int m2 = m0 + (r2 - node2 * nm);
    size_t obase = ((size_t)node2 * MTOT + m2) * CH + c16;
    #pragma unroll
    for (int ct = 0; ct < 8; ++ct) {
      float v = acc[ct][i];
      if (l == 0) v += bias[ct * 16 + c16];
      v *= scale;
      if (YBF) ((unsigned short*)Yv)[obase + ct * 16] = f2b(v);
      else     ((float*)Yv)[obase + ct * 16] = v;
    }
  }
}

// ---------------- gather + 4-way aggregate + fused TP ----------------------
// EXACT Round-0 verified structure (writes dif bf16; W2 runs as a separate
// so3lin_mfma launch — fusion was measured slower, R0 vs R1).
// Single addition (R5-verified): neighbors visited in idx-QUARTILE order
// (4-ballot rank sort into sPerm) so all blocks sweep the 9.4 MB table in
// 4 loose phases of ~2.35 MB each -> phase working set fits the 4 MB XCD L2.
// fp32 sum reorder only (commutative up to rounding; threshold has 4x slack).
__global__ __launch_bounds__(256) void agg_tp_b(
    const unsigned short* __restrict__ X,   // eh1 bf16 [NN,9,128]
    const float* __restrict__ pos,
    const float* __restrict__ exp_pos,
    const float* __restrict__ alpha,
    const int*   __restrict__ idx,
    const float* __restrict__ tpw,
    unsigned short* __restrict__ D)         // diff bf16 [NN,9,128]
{
  __shared__ int   sIdx[4][16];
  __shared__ float sAl[4][128];
  __shared__ float sEy[4][48];
  __shared__ float sY[4][4];
  __shared__ unsigned char sPerm[4][16];
  const int t = threadIdx.x, wave = t >> 6, lane = t & 63;
  const int b = blockIdx.x * 4 + wave;

  if (lane < 16) sIdx[wave][lane] = idx[b * 16 + lane];
  sAl[wave][lane]      = alpha[b * 128 + lane];
  sAl[wave][lane + 64] = alpha[b * 128 + lane + 64];
  if (lane < 3) sY[wave][lane] = YSf * pos[b * 3 + lane];
  __syncthreads();
  if (lane < 48) {
    int j = lane / 3, cmp = lane - 3 * j;
    sEy[wave][lane] = YSf * exp_pos[sIdx[wave][j] * 3 + cmp];
  }

  // ---- bucket-rank sort of the 16 neighbors by idx quartile (R5) ----
  {
    int key = (lane < 16) ? (sIdx[wave][lane] >> 10) : 7;   // 0..3 valid
    unsigned m0 = (unsigned)__ballot(key == 0) & 0xFFFFu;
    unsigned m1 = (unsigned)__ballot(key == 1) & 0xFFFFu;
    unsigned m2 = (unsigned)__ballot(key == 2) & 0xFFFFu;
    unsigned m3 = (unsigned)__ballot(key == 3) & 0xFFFFu;
    if (lane < 16) {
      unsigned below = (1u << lane) - 1u;
      int pos;
      if (key == 0)      pos = __popc(m0 & below);
      else if (key == 1) pos = __popc(m0) + __popc(m1 & below);
      else if (key == 2) pos = __popc(m0) + __popc(m1) + __popc(m2 & below);
      else               pos = __popc(m0) + __popc(m1) + __popc(m2) + __popc(m3 & below);
      sPerm[wave][pos] = (unsigned char)lane;
    }
  }
  __syncthreads();

  const int h = lane >> 3;
  const int c0 = lane * 2;
  f32x2 A0[9] = {}, A1[9] = {}, A2[9] = {}, A3[9] = {};
  #pragma unroll 2
  for (int jj = 0; jj < 16; ++jj) {
    const int j = sPerm[wave][jj];
    float al = sAl[wave][j * 8 + h];
    float e0 = al * sEy[wave][j * 3 + 0];
    float e1 = al * sEy[wave][j * 3 + 1];
    float e2 = al * sEy[wave][j * 3 + 2];
    f32x2 alv = {al, al};
    f32x2 e0v = {e0, e0};
    f32x2 e1v = {e1, e1};
    f32x2 e2v = {e2, e2};
    const unsigned short* xp = X + (size_t)sIdx[wave][j] * (MTOT * CH) + c0;
    #pragma unroll
    for (int m = 0; m < 9; ++m) {
      unsigned v = *(const unsigned*)(xp + m * CH);
      f32x2 x;
      x.x = __builtin_bit_cast(float, v << 16);
      x.y = __builtin_bit_cast(float, v & 0xFFFF0000u);
      A0[m] += alv * x; A1[m] += e0v * x; A2[m] += e1v * x; A3[m] += e2v * x;
    }
  }

  const float y0 = sY[wave][0], yv1 = sY[wave][1], y2 = sY[wave][2];
  float OUT[9][2];
  #pragma unroll
  for (int ch = 0; ch < 2; ++ch) {
    const int c = c0 + ch;
    const float w0 = tpw[c], w1 = tpw[CH + c], w2 = tpw[2 * CH + c];
    const float w3 = tpw[3 * CH + c], w4 = tpw[4 * CH + c], w5 = tpw[5 * CH + c];
    const float x0 = A0[0][ch];
    const float p0 = A0[1][ch], p1 = A0[2][ch], p2 = A0[3][ch];
    const float d0 = A0[4][ch], d1 = A0[5][ch], d2 = A0[6][ch], d3 = A0[7][ch], d4 = A0[8][ch];

    float r0 = w1 * S3f * (p0 * y0 + p1 * yv1 + p2 * y2);
    float r1 = w0 * x0 * y0 + w2 * S2f * (p1 * y2 - p2 * yv1)
             + w4 * (CUf * (d0 * y2 + d1 * yv1 - d4 * y0) - CVf * d2 * y0);
    float r2 = w0 * x0 * yv1 + w2 * S2f * (p2 * y0 - p0 * y2)
             + w4 * (CUf * (d1 * y0 + d3 * y2) + CWf * d2 * yv1);
    float r3 = w0 * x0 * y2 + w2 * S2f * (p0 * yv1 - p1 * y0)
             + w4 * (CUf * (d0 * y0 + d4 * y2 + d3 * yv1) - CVf * d2 * y2);
    float r4 = w3 * S2f * (p0 * y2 + p2 * y0)
             + w5 * (CAf * (d3 * y2 - d1 * y0) - 2.f * CAf * d4 * yv1);
    float r5 = w3 * S2f * (p0 * yv1 + p1 * y0)
             + w5 * (CAf * (d0 * y0 - d3 * yv1 + d4 * y2) + S2f * d2 * y2);
    float r6 = w3 * (CA2f * p1 * yv1 - CAf * (p0 * y0 + p2 * y2))
             + w5 * S2f * (d3 * y0 - d1 * y2);
    float r7 = w3 * S2f * (p1 * y2 + p2 * yv1)
             + w5 * (CAf * (d1 * yv1 - d0 * y2 + d4 * y0) - S2f * d2 * y0);
    float r8 = w3 * S2f * (p2 * y2 - p0 * y0)
             + w5 * CAf * (2.f * d0 * yv1 - d1 * y2 - d3 * y0);

    float q0 = w1 * S3f * (A1[1][ch] + A2[2][ch] + A3[3][ch]);
    float q1 = w0 * A1[0][ch] + w2 * S2f * (A3[2][ch] - A2[3][ch])
             + w4 * (CUf * (A3[4][ch] + A2[5][ch] - A1[8][ch]) - CVf * A1[6][ch]);
    float q2 = w0 * A2[0][ch] + w2 * S2f * (A1[3][ch] - A3[1][ch])
             + w4 * (CUf * (A1[5][ch] + A3[7][ch]) + CWf * A2[6][ch]);
    float q3 = w0 * A3[0][ch] + w2 * S2f * (A2[1][ch] - A1[2][ch])
             + w4 * (CUf * (A1[4][ch] + A3[8][ch] + A2[7][ch]) - CVf * A3[6][ch]);
    float q4 = w3 * S2f * (A3[1][ch] + A1[3][ch])
             + w5 * (CAf * (A3[7][ch] - A1[5][ch]) - 2.f * CAf * A2[8][ch]);
    float q5 = w3 * S2f * (A2[1][ch] + A1[2][ch])
             + w5 * (CAf * (A1[4][ch] - A2[7][ch] + A3[8][ch]) + S2f * A3[6][ch]);
    float q6 = w3 * (CA2f * A2[2][ch] - CAf * (A1[1][ch] + A3[3][ch]))
             + w5 * S2f * (A1[7][ch] - A3[5][ch]);
    float q7 = w3 * S2f * (A3[2][ch] + A2[3][ch])
             + w5 * (CAf * (A2[5][ch] - A3[4][ch] + A1[8][ch]) - S2f * A1[6][ch]);
    float q8 = w3 * S2f * (A3[3][ch] - A1[1][ch])
             + w5 * CAf * (2.f * A2[4][ch] - A3[5][ch] - A1[7][ch]);

    OUT[0][ch] = r0 - q0; OUT[1][ch] = r1 - q1; OUT[2][ch] = r2 - q2;
    OUT[3][ch] = r3 - q3; OUT[4][ch] = r4 - q4; OUT[5][ch] = r5 - q5;
    OUT[6][ch] = r6 - q6; OUT[7][ch] = r7 - q7; OUT[8][ch] = r8 - q8;
  }

  #pragma unroll
  for (int m = 0; m < 9; ++m) {
    unsigned dw = (unsigned)f2b(OUT[m][0]) | ((unsigned)f2b(OUT[m][1]) << 16);
    *(unsigned*)(D + ((size_t)b * MTOT + m) * CH + c0) = dw;
  }
}

extern "C" void kernel_launch(void* const* d_in, const int* in_sizes, int n_in,
                              void* d_out, int out_size, void* d_ws, size_t ws_size,
                              hipStream_t stream) {
  (void)in_sizes; (void)n_in; (void)out_size; (void)ws_size;
  const float* pos     = (const float*)d_in[0];
  const float* exp_pos = (const float*)d_in[1];
  // d_in[2] = h : unused by the reference computation
  const float* exp_h   = (const float*)d_in[3];
  const float* alpha   = (const float*)d_in[4];
  const int*   idx     = (const int*)d_in[5];
  const float* w1w     = (const float*)d_in[6];
  const float* w1b     = (const float*)d_in[7];
  const float* w2w     = (const float*)d_in[8];
  const float* w2b     = (const float*)d_in[9];
  const float* tpw     = (const float*)d_in[10];
  float* out = (float*)d_out;

  unsigned short* eh1 = (unsigned short*)d_ws;                  // bf16 [4096*9*128]
  unsigned short* dif = eh1 + (size_t)NN * MTOT * CH;           // bf16 [4096*9*128]
  unsigned short* w1s = dif + (size_t)NN * MTOT * CH;           // bf16 swizzled [3*16384]
  unsigned short* w2s = w1s + 3 * 16384;                        // bf16 swizzled [3*16384]

  wprep<<<48, 256, 0, stream>>>(w1w, w2w, w1s, w2s);
  so3lin_mfma<0, 1, 0><<<576, 256, 0, stream>>>(exp_h, w1s, w1b, eh1);
  agg_tp_b<<<NN / 4, 256, 0, stream>>>(eh1, pos, exp_pos, alpha, idx, tpw, dif);
  so3lin_mfma<1, 0, 1><<<576, 256, 0, stream>>>(dif, w2s, w2b, out);
}

// Round 7
// 131.341 us; speedup vs baseline: 1.1775x; 1.0063x over previous
//
#include <hip/hip_runtime.h>

#define NN 4096
#define MTOT 9
#define CH 128

// -------- Wigner-3j / TP constants (verified correct in earlier passes) ----
#define S3f 0.57735026918962576f   // 1/sqrt(3)
#define S2f 0.70710678118654752f   // 1/sqrt(2)
#define CUf 0.54772255750516611f   // sqrt(3/10)
#define CVf 0.31622776601683794f   // sqrt(1/10)
#define CWf 0.63245553203367587f   // 2/sqrt(10)
#define CAf 0.40824829046386302f   // 1/sqrt(6)
#define CA2f 0.81649658092772603f  // 2/sqrt(6)
#define YSf ((float)(2.04665350914 * 0.48860251190291992))

typedef __attribute__((ext_vector_type(8))) short short8;
typedef __attribute__((ext_vector_type(4))) float f32x4;
typedef __attribute__((ext_vector_type(2))) float f32x2;

__device__ __forceinline__ unsigned short f2b(float f) {
  unsigned u = __builtin_bit_cast(unsigned, f);
  u += 0x7FFFu + ((u >> 16) & 1u);           // RNE
  return (unsigned short)(u >> 16);
}

// ---------------- W pre-swizzle: fp32 [3,128,128] -> bf16 frag-order -------
// out[l*16384 + (((n>>4)*16 + kq)*16 + (n&15))*8 + j] = W[l][kq*8+j][n]
__global__ __launch_bounds__(256) void wprep(
    const float* __restrict__ w1, const float* __restrict__ w2,
    unsigned short* __restrict__ o1, unsigned short* __restrict__ o2)
{
  int g = blockIdx.x * 256 + threadIdx.x;    // 12288 total
  const float* W = w1;
  unsigned short* O = o1;
  int r = g;
  if (r >= 6144) { r -= 6144; W = w2; O = o2; }
  int l  = r >> 11;          // 2048 per l
  int r2 = r & 2047;
  int n  = r2 >> 4;
  int kq = r2 & 15;
  const float* src = W + l * 16384 + kq * 8 * CH + n;
  short8 v;
  #pragma unroll
  for (int j = 0; j < 8; ++j) v[j] = (short)f2b(src[j * CH]);
  *(short8*)(O + (size_t)l * 16384 + (((n >> 4) * 16 + kq) * 16 + (n & 15)) * 8) = v;
}

// ---------------- so3_linear via MFMA 16x16x32 bf16 ----------------
// W arrives pre-swizzled bf16; staging is 8 contiguous dwordx4 + b128 writes.
template <int XBF, int YBF, int NORM>
__global__ __launch_bounds__(256) void so3lin_mfma(
    const void* __restrict__ Xv, const unsigned short* __restrict__ Wsw,
    const float* __restrict__ bias, void* __restrict__ Yv)
{
  __shared__ unsigned short Bs[16384];   // 32 KB frag-order bf16 W_l
  const int bid = blockIdx.x;
  int l, blk0, m0, nm;
  if (bid < 64)       { l = 0; blk0 = bid;       m0 = 0; nm = 1; }
  else if (bid < 256) { l = 1; blk0 = bid - 64;  m0 = 1; nm = 3; }
  else                { l = 2; blk0 = bid - 256; m0 = 4; nm = 5; }
  const int t = threadIdx.x;

  {
    const float4* src = (const float4*)(Wsw + (size_t)l * 16384);
    float4* dst = (float4*)Bs;
    #pragma unroll
    for (int i = 0; i < 8; ++i) dst[t + i * 256] = src[t + i * 256];
  }
  __syncthreads();

  const int lane = t & 63;
  const int wave = t >> 6;
  const int c16  = lane & 15;
  const int quad = lane >> 4;
  const int rb   = (blk0 * 4 + wave) * 16;

  const int ra = rb + c16;
  const int nodeA = ra / nm;
  const int mA = m0 + (ra - nodeA * nm);
  const size_t abase = ((size_t)nodeA * MTOT + mA) * CH + quad * 8;

  f32x4 acc[8] = {};
  #pragma unroll
  for (int kk = 0; kk < CH; kk += 32) {
    short8 afrag;
    if (XBF) {
      afrag = *(const short8*)((const unsigned short*)Xv + abase + kk);
    } else {
      const float* xp = (const float*)Xv + abase + kk;
      float4 f0 = *(const float4*)xp;
      float4 f1 = *(const float4*)(xp + 4);
      afrag = (short8){(short)f2b(f0.x), (short)f2b(f0.y), (short)f2b(f0.z), (short)f2b(f0.w),
                       (short)f2b(f1.x), (short)f2b(f1.y), (short)f2b(f1.z), (short)f2b(f1.w)};
    }
    const int kq = (kk >> 3) + quad;
    #pragma unroll
    for (int ct = 0; ct < 8; ++ct) {
      short8 bfrag = *(const short8*)&Bs[((ct * 16 + kq) * 16 + c16) * 8];
      acc[ct] = __builtin_amdgcn_mfma_f32_16x16x32_bf16(afrag, bfrag, acc[ct], 0, 0, 0);
    }
  }

  const float scale = NORM ? (l == 0 ? 1.0f : (l == 1 ? S3f : S2f)) : 1.0f;
  #pragma unroll
  for (int i = 0; i < 4; ++i) {
    int r2 = rb + quad * 4 + i;
    int node2 = r2 / nm;
    int m2 = m0 + (r2 - node2 * nm);
    size_t obase = ((size_t)node2 * MTOT + m2) * CH + c16;
    #pragma unroll
    for (int ct = 0; ct < 8; ++ct) {
      float v = acc[ct][i];
      if (l == 0) v += bias[ct * 16 + c16];
      v *= scale;
      if (YBF) ((unsigned short*)Yv)[obase + ct * 16] = f2b(v);
      else     ((float*)Yv)[obase + ct * 16] = v;
    }
  }
}

// ---------------- gather + 4-way aggregate + fused TP ----------------------
// R6-verified structure (writes dif bf16; W2 as separate so3lin launch).
// Change vs R6: neighbors visited in FULLY ASCENDING idx order (rank sort,
// 16 LDS compares/lane) instead of quartile buckets -> every block sweeps
// the 9.4 MB table monotonically; concurrent working set at gather step jj
// clusters around the jj/16 quantile (~1-2 MB), inside the 4 MB XCD L2.
// fp32 sum reorder only (commutative up to rounding; threshold has 4x slack).
__global__ __launch_bounds__(256) void agg_tp_b(
    const unsigned short* __restrict__ X,   // eh1 bf16 [NN,9,128]
    const float* __restrict__ pos,
    const float* __restrict__ exp_pos,
    const float* __restrict__ alpha,
    const int*   __restrict__ idx,
    const float* __restrict__ tpw,
    unsigned short* __restrict__ D)         // diff bf16 [NN,9,128]
{
  __shared__ int   sIdx[4][16];
  __shared__ float sAl[4][128];
  __shared__ float sEy[4][48];
  __shared__ float sY[4][4];
  __shared__ unsigned char sPerm[4][16];
  const int t = threadIdx.x, wave = t >> 6, lane = t & 63;
  const int b = blockIdx.x * 4 + wave;

  if (lane < 16) sIdx[wave][lane] = idx[b * 16 + lane];
  sAl[wave][lane]      = alpha[b * 128 + lane];
  sAl[wave][lane + 64] = alpha[b * 128 + lane + 64];
  if (lane < 3) sY[wave][lane] = YSf * pos[b * 3 + lane];
  __syncthreads();
  if (lane < 48) {
    int j = lane / 3, cmp = lane - 3 * j;
    sEy[wave][lane] = YSf * exp_pos[sIdx[wave][j] * 3 + cmp];
  }

  // ---- full rank sort of the 16 neighbors by idx (ties broken by slot) ----
  if (lane < 16) {
    const int my = sIdx[wave][lane];
    int rank = 0;
    #pragma unroll
    for (int k = 0; k < 16; ++k) {
      int other = sIdx[wave][k];
      rank += (other < my) || (other == my && k < lane);
    }
    sPerm[wave][rank] = (unsigned char)lane;
  }
  __syncthreads();

  const int h = lane >> 3;
  const int c0 = lane * 2;
  f32x2 A0[9] = {}, A1[9] = {}, A2[9] = {}, A3[9] = {};
  #pragma unroll 2
  for (int jj = 0; jj < 16; ++jj) {
    const int j = sPerm[wave][jj];
    float al = sAl[wave][j * 8 + h];
    float e0 = al * sEy[wave][j * 3 + 0];
    float e1 = al * sEy[wave][j * 3 + 1];
    float e2 = al * sEy[wave][j * 3 + 2];
    f32x2 alv = {al, al};
    f32x2 e0v = {e0, e0};
    f32x2 e1v = {e1, e1};
    f32x2 e2v = {e2, e2};
    const unsigned short* xp = X + (size_t)sIdx[wave][j] * (MTOT * CH) + c0;
    #pragma unroll
    for (int m = 0; m < 9; ++m) {
      unsigned v = *(const unsigned*)(xp + m * CH);
      f32x2 x;
      x.x = __builtin_bit_cast(float, v << 16);
      x.y = __builtin_bit_cast(float, v & 0xFFFF0000u);
      A0[m] += alv * x; A1[m] += e0v * x; A2[m] += e1v * x; A3[m] += e2v * x;
    }
  }

  const float y0 = sY[wave][0], yv1 = sY[wave][1], y2 = sY[wave][2];
  float OUT[9][2];
  #pragma unroll
  for (int ch = 0; ch < 2; ++ch) {
    const int c = c0 + ch;
    const float w0 = tpw[c], w1 = tpw[CH + c], w2 = tpw[2 * CH + c];
    const float w3 = tpw[3 * CH + c], w4 = tpw[4 * CH + c], w5 = tpw[5 * CH + c];
    const float x0 = A0[0][ch];
    const float p0 = A0[1][ch], p1 = A0[2][ch], p2 = A0[3][ch];
    const float d0 = A0[4][ch], d1 = A0[5][ch], d2 = A0[6][ch], d3 = A0[7][ch], d4 = A0[8][ch];

    float r0 = w1 * S3f * (p0 * y0 + p1 * yv1 + p2 * y2);
    float r1 = w0 * x0 * y0 + w2 * S2f * (p1 * y2 - p2 * yv1)
             + w4 * (CUf * (d0 * y2 + d1 * yv1 - d4 * y0) - CVf * d2 * y0);
    float r2 = w0 * x0 * yv1 + w2 * S2f * (p2 * y0 - p0 * y2)
             + w4 * (CUf * (d1 * y0 + d3 * y2) + CWf * d2 * yv1);
    float r3 = w0 * x0 * y2 + w2 * S2f * (p0 * yv1 - p1 * y0)
             + w4 * (CUf * (d0 * y0 + d4 * y2 + d3 * yv1) - CVf * d2 * y2);
    float r4 = w3 * S2f * (p0 * y2 + p2 * y0)
             + w5 * (CAf * (d3 * y2 - d1 * y0) - 2.f * CAf * d4 * yv1);
    float r5 = w3 * S2f * (p0 * yv1 + p1 * y0)
             + w5 * (CAf * (d0 * y0 - d3 * yv1 + d4 * y2) + S2f * d2 * y2);
    float r6 = w3 * (CA2f * p1 * yv1 - CAf * (p0 * y0 + p2 * y2))
             + w5 * S2f * (d3 * y0 - d1 * y2);
    float r7 = w3 * S2f * (p1 * y2 + p2 * yv1)
             + w5 * (CAf * (d1 * yv1 - d0 * y2 + d4 * y0) - S2f * d2 * y0);
    float r8 = w3 * S2f * (p2 * y2 - p0 * y0)
             + w5 * CAf * (2.f * d0 * yv1 - d1 * y2 - d3 * y0);

    float q0 = w1 * S3f * (A1[1][ch] + A2[2][ch] + A3[3][ch]);
    float q1 = w0 * A1[0][ch] + w2 * S2f * (A3[2][ch] - A2[3][ch])
             + w4 * (CUf * (A3[4][ch] + A2[5][ch] - A1[8][ch]) - CVf * A1[6][ch]);
    float q2 = w0 * A2[0][ch] + w2 * S2f * (A1[3][ch] - A3[1][ch])
             + w4 * (CUf * (A1[5][ch] + A3[7][ch]) + CWf * A2[6][ch]);
    float q3 = w0 * A3[0][ch] + w2 * S2f * (A2[1][ch] - A1[2][ch])
             + w4 * (CUf * (A1[4][ch] + A3[8][ch] + A2[7][ch]) - CVf * A3[6][ch]);
    float q4 = w3 * S2f * (A3[1][ch] + A1[3][ch])
             + w5 * (CAf * (A3[7][ch] - A1[5][ch]) - 2.f * CAf * A2[8][ch]);
    float q5 = w3 * S2f * (A2[1][ch] + A1[2][ch])
             + w5 * (CAf * (A1[4][ch] - A2[7][ch] + A3[8][ch]) + S2f * A3[6][ch]);
    float q6 = w3 * (CA2f * A2[2][ch] - CAf * (A1[1][ch] + A3[3][ch]))
             + w5 * S2f * (A1[7][ch] - A3[5][ch]);
    float q7 = w3 * S2f * (A3[2][ch] + A2[3][ch])
             + w5 * (CAf * (A2[5][ch] - A3[4][ch] + A1[8][ch]) - S2f * A1[6][ch]);
    float q8 = w3 * S2f * (A3[3][ch] - A1[1][ch])
             + w5 * CAf * (2.f * A2[4][ch] - A3[5][ch] - A1[7][ch]);

    OUT[0][ch] = r0 - q0; OUT[1][ch] = r1 - q1; OUT[2][ch] = r2 - q2;
    OUT[3][ch] = r3 - q3; OUT[4][ch] = r4 - q4; OUT[5][ch] = r5 - q5;
    OUT[6][ch] = r6 - q6; OUT[7][ch] = r7 - q7; OUT[8][ch] = r8 - q8;
  }

  #pragma unroll
  for (int m = 0; m < 9; ++m) {
    unsigned dw = (unsigned)f2b(OUT[m][0]) | ((unsigned)f2b(OUT[m][1]) << 16);
    *(unsigned*)(D + ((size_t)b * MTOT + m) * CH + c0) = dw;
  }
}

extern "C" void kernel_launch(void* const* d_in, const int* in_sizes, int n_in,
                              void* d_out, int out_size, void* d_ws, size_t ws_size,
                              hipStream_t stream) {
  (void)in_sizes; (void)n_in; (void)out_size; (void)ws_size;
  const float* pos     = (const float*)d_in[0];
  const float* exp_pos = (const float*)d_in[1];
  // d_in[2] = h : unused by the reference computation
  const float* exp_h   = (const float*)d_in[3];
  const float* alpha   = (const float*)d_in[4];
  const int*   idx     = (const int*)d_in[5];
  const float* w1w     = (const float*)d_in[6];
  const float* w1b     = (const float*)d_in[7];
  const float* w2w     = (const float*)d_in[8];
  const float* w2b     = (const float*)d_in[9];
  const float* tpw     = (const float*)d_in[10];
  float* out = (float*)d_out;

  unsigned short* eh1 = (unsigned short*)d_ws;                  // bf16 [4096*9*128]
  unsigned short* dif = eh1 + (size_t)NN * MTOT * CH;           // bf16 [4096*9*128]
  unsigned short* w1s = dif + (size_t)NN * MTOT * CH;           // bf16 swizzled [3*16384]
  unsigned short* w2s = w1s + 3 * 16384;                        // bf16 swizzled [3*16384]

  wprep<<<48, 256, 0, stream>>>(w1w, w2w, w1s, w2s);
  so3lin_mfma<0, 1, 0><<<576, 256, 0, stream>>>(exp_h, w1s, w1b, eh1);
  agg_tp_b<<<NN / 4, 256, 0, stream>>>(eh1, pos, exp_pos, alpha, idx, tpw, dif);
  so3lin_mfma<1, 0, 1><<<576, 256, 0, stream>>>(dif, w2s, w2b, out);
}